// Round 6
// baseline (305.527 us; speedup 1.0000x reference)
//
#include <hip/hip_runtime.h>
#include <hip/hip_bf16.h>
#include <stdint.h>

// SingleHeadAttention: B=8 T=2048 E=1024 A=1024, fp32 in/out, bf16 MFMA inside.
// Round 6 = R5 with ONE change: gemm256_core ds_reads software-pipelined one
// phase ahead (issue@p, counted-lgkm-wait@p+1) so LDS drains under MFMA.
// Staging re-streamed to 1 region/phase with counted vmcnt(8)/vmcnt(10).
// score/pv/transpose/cvt/grids unchanged from R5 (293.7 us baseline).

#define BB 8
#define TT 2048
#define EE 1024
#define AA 1024
#define MM (BB * TT)  // 16384

typedef short bf16x8 __attribute__((ext_vector_type(8)));
typedef float f32x4 __attribute__((ext_vector_type(4)));

#define GLOAD_LDS16(g, l)                                                      \
  __builtin_amdgcn_global_load_lds(                                            \
      (const __attribute__((address_space(1))) void*)(g),                      \
      (__attribute__((address_space(3))) void*)(l), 16, 0, 0)

#define SBAR()                               \
  do {                                       \
    __builtin_amdgcn_sched_barrier(0);       \
    __builtin_amdgcn_s_barrier();            \
    __builtin_amdgcn_sched_barrier(0);       \
  } while (0)

#define LGKM(n)                                               \
  do {                                                        \
    asm volatile("s_waitcnt lgkmcnt(" #n ")" ::: "memory");   \
    __builtin_amdgcn_sched_barrier(0);                        \
  } while (0)

#define VMCNT(n)                                              \
  do {                                                        \
    asm volatile("s_waitcnt vmcnt(" #n ")" ::: "memory");     \
    __builtin_amdgcn_sched_barrier(0);                        \
  } while (0)

#define MFMA16(a, b, c) __builtin_amdgcn_mfma_f32_16x16x32_bf16((a), (b), (c), 0, 0, 0)

// ---------------------------------------------------------------------------
// 256x256x(K) bt-GEMM core, BK=64, 8 waves (2M x 4N), per-wave 128x64.
// LDS/operand: [2 buf][2 ksub][256 row][32 kc] shorts, st_16x32 swizzle.
// Pipelined: reads issued one phase ahead, counted lgkm; staging 1 region per
// phase (stream ...B0,A0,B1 of t+1 | A1(t+1)@ph0, B0(t+2)@ph1, A0(t+2)@ph2,
// B1(t+2)@ph3...), counted vmcnt(8)@ph0 / vmcnt(10)@ph3.
// ---------------------------------------------------------------------------
__device__ __forceinline__ void gemm256_core(
    const short* __restrict__ gA, int lda, int a0row,
    const short* __restrict__ gB, int ldb, int b0row, int NT, short* As,
    short* Bs, f32x4 (*acc)[4]) {
  const int tid = threadIdx.x;
  const int lane = tid & 63;
  const int w = tid >> 6;
  const int lrow = lane & 15;
  const int lk8 = (lane >> 4) * 8;
  const int swz = ((lrow >> 3) & 1) << 4;
  const int wr = w >> 2, wc = w & 3;
  const int baseA = (((wr * 128 + lrow) * 32) + lk8) ^ swz;
  const int baseB = (((wc * 64 + lrow) * 32) + lk8) ^ swz;

  const short* pA[2];
  const short* pB[2];
#pragma unroll
  for (int i = 0; i < 2; ++i) {
    int chunk = 2 * w + i;
    int P = chunk * 1024 + lane * 16;           // phys byte in 16KB region
    int L = P ^ (((P >> 9) & 1) << 5);          // logical byte
    int row = L >> 6;
    int kb2 = (L & 63) >> 1;                    // shorts
    pA[i] = gA + (size_t)(a0row + row) * lda + kb2;
    pB[i] = gB + (size_t)(b0row + row) * ldb + kb2;
  }

#define STG_A(tl, s)                                                           \
  do {                                                                         \
    int _o = (tl) * 64 + (s) * 32;                                             \
    short* _d = As + (((tl) & 1) << 14) + ((s) << 13);                         \
    GLOAD_LDS16(pA[0] + _o, _d + (2 * w) * 512 + lane * 8);                    \
    GLOAD_LDS16(pA[1] + _o, _d + (2 * w + 1) * 512 + lane * 8);                \
  } while (0)
#define STG_B(tl, s)                                                           \
  do {                                                                         \
    int _o = (tl) * 64 + (s) * 32;                                             \
    short* _d = Bs + (((tl) & 1) << 14) + ((s) << 13);                         \
    GLOAD_LDS16(pB[0] + _o, _d + (2 * w) * 512 + lane * 8);                    \
    GLOAD_LDS16(pB[1] + _o, _d + (2 * w + 1) * 512 + lane * 8);                \
  } while (0)

  // Prologue: stream order [B0 A0 B1 A1](t0), [B0 A0 B1](t1).
  STG_B(0, 0); STG_A(0, 0); STG_B(0, 1); STG_A(0, 1);
  bf16x8 a0[4], b0[4];  // loop-carried: issued at ph3 for the NEXT tile
  if (NT > 1) {
    STG_B(1, 0); STG_A(1, 0); STG_B(1, 1);
    VMCNT(6);  // t0's 8 loads complete; t1's 6 in flight
  } else {
    VMCNT(0);
  }
  SBAR();
#pragma unroll
  for (int m = 0; m < 4; ++m) a0[m] = *(const bf16x8*)&As[baseA + m * 512];
#pragma unroll
  for (int n = 0; n < 4; ++n) b0[n] = *(const bf16x8*)&Bs[baseB + n * 512];

  for (int t = 0; t < NT; ++t) {
    const short* Ac = As + ((t & 1) << 14);
    const short* Bc = Bs + ((t & 1) << 14);
    const short* An = As + (((t + 1) & 1) << 14);
    const short* Bn = Bs + (((t + 1) & 1) << 14);
    bf16x8 a1[4], a2[4], a3[4], b1[4];

    // ---- ph0: STG A-k1(t+1); vmcnt; SBAR; issue {a1,a2}; lgkm(8)[a0,b0];
    //           MFMA a0*b0 -> acc[0..3]
    if (t < NT - 1) {
      STG_A(t + 1, 1);
      VMCNT(8);   // waits A-k1(t); leaves t+1's 4 regions
    } else {
      VMCNT(0);
    }
    SBAR();
#pragma unroll
    for (int m = 0; m < 4; ++m)
      a1[m] = *(const bf16x8*)&Ac[baseA + (m + 4) * 512];
#pragma unroll
    for (int m = 0; m < 4; ++m)
      a2[m] = *(const bf16x8*)&Ac[8192 + baseA + m * 512];
    LGKM(8);  // waits a0,b0; leaves a1,a2
    __builtin_amdgcn_s_setprio(1);
#pragma unroll
    for (int m = 0; m < 4; ++m)
#pragma unroll
      for (int n = 0; n < 4; ++n) acc[m][n] = MFMA16(a0[m], b0[n], acc[m][n]);
    __builtin_amdgcn_s_setprio(0);
    SBAR();

    // ---- ph1: STG B-k0(t+2); SBAR; issue {b1}; lgkm(4)[a1,a2];
    //           MFMA a1*b0 -> acc[4..7]
    if (t < NT - 2) STG_B(t + 2, 0);
    SBAR();
#pragma unroll
    for (int n = 0; n < 4; ++n)
      b1[n] = *(const bf16x8*)&Bc[8192 + baseB + n * 512];
    LGKM(4);  // waits a1,a2; leaves b1
    __builtin_amdgcn_s_setprio(1);
#pragma unroll
    for (int m = 0; m < 4; ++m)
#pragma unroll
      for (int n = 0; n < 4; ++n)
        acc[m + 4][n] = MFMA16(a1[m], b0[n], acc[m + 4][n]);
    __builtin_amdgcn_s_setprio(0);
    SBAR();

    // ---- ph2: STG A-k0(t+2); SBAR; issue {a3}; lgkm(4)[b1];
    //           MFMA a2*b1 -> acc[0..3]
    if (t < NT - 2) STG_A(t + 2, 0);
    SBAR();
#pragma unroll
    for (int m = 0; m < 4; ++m)
      a3[m] = *(const bf16x8*)&Ac[8192 + baseA + (m + 4) * 512];
    LGKM(4);  // waits b1; leaves a3
    __builtin_amdgcn_s_setprio(1);
#pragma unroll
    for (int m = 0; m < 4; ++m)
#pragma unroll
      for (int n = 0; n < 4; ++n) acc[m][n] = MFMA16(a2[m], b1[n], acc[m][n]);
    __builtin_amdgcn_s_setprio(0);
    SBAR();

    // ---- ph3: STG B-k1(t+2); vmcnt; SBAR; issue {a0,b0}(t+1); lgkm(8)[a3];
    //           MFMA a3*b1 -> acc[4..7]
    if (t < NT - 2) {
      STG_B(t + 2, 1);
      VMCNT(10);  // waits A-k0(t+1) (needed by a0 next); leaves 5 regions
    } else if (t == NT - 2) {
      VMCNT(4);   // tail: waits A-k0(NT-1); leaves B-k1,A-k1(NT-1)
    }
    SBAR();
    if (t < NT - 1) {
#pragma unroll
      for (int m = 0; m < 4; ++m) a0[m] = *(const bf16x8*)&An[baseA + m * 512];
#pragma unroll
      for (int n = 0; n < 4; ++n) b0[n] = *(const bf16x8*)&Bn[baseB + n * 512];
      LGKM(8);  // waits a3; leaves next-tile a0,b0
    } else {
      LGKM(0);
    }
    __builtin_amdgcn_s_setprio(1);
#pragma unroll
    for (int m = 0; m < 4; ++m)
#pragma unroll
      for (int n = 0; n < 4; ++n)
        acc[m + 4][n] = MFMA16(a3[m], b1[n], acc[m + 4][n]);
    __builtin_amdgcn_s_setprio(0);
    SBAR();
  }
#undef STG_A
#undef STG_B
}

// ---------------------------------------------------------------------------
// Fused QKV: grid 768 x 512thr, XCD-chunked (R5 mapping).
// ---------------------------------------------------------------------------
__global__ __launch_bounds__(512, 2) void qkv_gemm8(
    const short* __restrict__ xb, const short* __restrict__ Wb,
    short* __restrict__ qkv) {
  __shared__ __align__(16) short As[32768];
  __shared__ __align__(16) short Bs[32768];
  int f = blockIdx.x;
  int s = (f & 7) * 96 + (f >> 3);  // XCD-chunked (768 % 8 == 0)
  int mt = s / 12, nt = s % 12;
  int z = nt >> 2, ntl = nt & 3;
  const short* gB = Wb + (size_t)z * AA * EE + (size_t)(ntl * 256) * EE;
  f32x4 acc[8][4];
#pragma unroll
  for (int m = 0; m < 8; ++m)
#pragma unroll
    for (int n = 0; n < 4; ++n) acc[m][n] = (f32x4){0.f, 0.f, 0.f, 0.f};
  gemm256_core(xb, EE, mt * 256, gB, EE, 0, EE / 64, As, Bs, acc);

  short* o = qkv + (size_t)z * MM * AA;
  int lane = threadIdx.x & 63, w = threadIdx.x >> 6, wr = w >> 2, wc = w & 3;
  int lrow = lane & 15, lk4 = (lane >> 4) * 4;
  int row0 = mt * 256 + wr * 128;
  int col0 = ntl * 256 + wc * 64;
#pragma unroll
  for (int m = 0; m < 8; ++m)
#pragma unroll
    for (int n = 0; n < 4; ++n)
#pragma unroll
      for (int r = 0; r < 4; ++r) {
        int row = row0 + m * 16 + lk4 + r;
        int col = col0 + n * 16 + lrow;
        __hip_bfloat16 h = __float2bfloat16(acc[m][n][r]);
        o[(size_t)row * AA + col] = *(short*)&h;
      }
}

// ---------------------------------------------------------------------------
// R1-style 128x128 helpers (score + pv bodies) — unchanged.
// ---------------------------------------------------------------------------
__device__ __forceinline__ void stage_tile(const short* __restrict__ g,
                                           size_t stride, short* lds, int tid) {
#pragma unroll
  for (int r = 0; r < 4; ++r) {
    int t = r * 256 + tid;
    int row = t >> 3;
    int c = (t & 7) * 8;
    GLOAD_LDS16(g + (size_t)row * stride + c, lds + (size_t)t * 8);
  }
}

__device__ __forceinline__ void mfma_step(const short* As, const short* Bs,
                                          f32x4 acc[4][4], int lane, int wr,
                                          int wc) {
  int lrow = lane & 15;
  int lk = (lane >> 4) * 8;
#pragma unroll
  for (int kk = 0; kk < 64; kk += 32) {
    bf16x8 a[4], b[4];
#pragma unroll
    for (int i = 0; i < 4; ++i)
      a[i] = *(const bf16x8*)&As[(wr * 64 + i * 16 + lrow) * 64 + kk + lk];
#pragma unroll
    for (int j = 0; j < 4; ++j)
      b[j] = *(const bf16x8*)&Bs[(wc * 64 + j * 16 + lrow) * 64 + kk + lk];
#pragma unroll
    for (int i = 0; i < 4; ++i)
#pragma unroll
      for (int j = 0; j < 4; ++j)
        acc[i][j] =
            __builtin_amdgcn_mfma_f32_16x16x32_bf16(a[i], b[j], acc[i][j], 0, 0, 0);
  }
}

__global__ void cvt_bf16(const float* __restrict__ src, short* __restrict__ dst,
                         int n4) {
  int stride = gridDim.x * blockDim.x;
  for (int i = blockIdx.x * blockDim.x + threadIdx.x; i < n4; i += stride) {
    float4 v = ((const float4*)src)[i];
    __hip_bfloat16 h0 = __float2bfloat16(v.x);
    __hip_bfloat16 h1 = __float2bfloat16(v.y);
    __hip_bfloat16 h2 = __float2bfloat16(v.z);
    __hip_bfloat16 h3 = __float2bfloat16(v.w);
    short4 o;
    o.x = *(short*)&h0;
    o.y = *(short*)&h1;
    o.z = *(short*)&h2;
    o.w = *(short*)&h3;
    ((short4*)dst)[i] = o;
  }
}

__global__ void cvt_w3(const float* __restrict__ wq, const float* __restrict__ wk,
                       const float* __restrict__ wv, short* __restrict__ dst) {
  const int n4 = AA * EE / 4;
  int stride = gridDim.x * blockDim.x;
  for (int i = blockIdx.x * blockDim.x + threadIdx.x; i < 3 * n4; i += stride) {
    const float* src = (i < n4) ? wq : (i < 2 * n4 ? wk : wv);
    int ii = (i < n4) ? i : (i < 2 * n4 ? i - n4 : i - 2 * n4);
    float4 v = ((const float4*)src)[ii];
    __hip_bfloat16 h0 = __float2bfloat16(v.x);
    __hip_bfloat16 h1 = __float2bfloat16(v.y);
    __hip_bfloat16 h2 = __float2bfloat16(v.z);
    __hip_bfloat16 h3 = __float2bfloat16(v.w);
    short4 o;
    o.x = *(short*)&h0;
    o.y = *(short*)&h1;
    o.z = *(short*)&h2;
    o.w = *(short*)&h3;
    ((short4*)dst)[i] = o;
  }
}

__global__ __launch_bounds__(256) void transpose_v(const short* __restrict__ Vb,
                                                   short* __restrict__ Vt) {
  __shared__ __align__(16) short lds[64 * 72];
  int t0 = blockIdx.x * 64;
  int d0 = blockIdx.y * 64;
  int b = blockIdx.z;
  int tid = threadIdx.x;
  const short* src = Vb + ((size_t)b * TT + t0) * AA + d0;
#pragma unroll
  for (int r = 0; r < 2; ++r) {
    int t = r * 256 + tid;
    int row = t >> 3;
    int c = (t & 7) * 8;
    *(bf16x8*)&lds[row * 72 + c] = *(const bf16x8*)&src[(size_t)row * AA + c];
  }
  __syncthreads();
  short* dst = Vt + ((size_t)b * AA + d0) * TT + t0;
#pragma unroll
  for (int r = 0; r < 2; ++r) {
    int t = r * 256 + tid;
    int d = t >> 3;
    int c = (t & 7) * 8;
    bf16x8 wv;
#pragma unroll
    for (int e = 0; e < 8; ++e) wv[e] = lds[(c + e) * 72 + d];
    *(bf16x8*)&dst[(size_t)d * TT + c] = wv;
  }
}

// ---------------------------------------------------------------------------
// Scores: compact lower-triangle grid 1088 (8 b x 136 tri), XCD = batch.
// ---------------------------------------------------------------------------
__global__ __launch_bounds__(256) void score_gemm(const short* __restrict__ Qb,
                                                  const short* __restrict__ Kb,
                                                  short* __restrict__ Pu,
                                                  float* __restrict__ lsum) {
  int f = blockIdx.x;
  int b = f & 7;
  int j = f >> 3;  // tri index in [0,136)
  int mt = 0;
  while ((mt + 1) * (mt + 2) / 2 <= j) ++mt;
  int nt = j - mt * (mt + 1) / 2;
  int q0 = mt * 128, c0 = nt * 128;

  __shared__ __align__(16) short As[128 * 64];
  __shared__ __align__(16) short Bs[128 * 64];
  int tid = threadIdx.x;
  int lane = tid & 63, wid = tid >> 6, wr = wid >> 1, wc = wid & 1;
  const short* Q = Qb + (size_t)b * TT * AA;
  const short* K = Kb + (size_t)b * TT * AA;
  f32x4 acc[4][4];
#pragma unroll
  for (int i = 0; i < 4; ++i)
#pragma unroll
    for (int jj = 0; jj < 4; ++jj) acc[i][jj] = (f32x4){0.f, 0.f, 0.f, 0.f};

  for (int k0 = 0; k0 < AA; k0 += 64) {
    stage_tile(Q + (size_t)q0 * AA + k0, AA, As, tid);
    stage_tile(K + (size_t)c0 * AA + k0, AA, Bs, tid);
    __syncthreads();
    mfma_step(As, Bs, acc, lane, wr, wc);
    __syncthreads();
  }
  const float scale = 0.03125f;  // 1/sqrt(1024)
  short* P = Pu + (size_t)b * TT * TT;
  int lrow = lane & 15, lk4 = (lane >> 4) * 4;
#pragma unroll
  for (int i = 0; i < 4; ++i) {
#pragma unroll
    for (int r = 0; r < 4; ++r) {
      int q = q0 + wr * 64 + i * 16 + lk4 + r;
      float rs = 0.f;
#pragma unroll
      for (int jj = 0; jj < 4; ++jj) {
        int kx = c0 + wc * 64 + jj * 16 + lrow;
        float e = (kx <= q) ? __expf(acc[i][jj][r] * scale) : 0.f;
        rs += e;
        __hip_bfloat16 h = __float2bfloat16(e);
        P[(size_t)q * TT + kx] = *(short*)&h;
      }
      rs += __shfl_xor(rs, 1);
      rs += __shfl_xor(rs, 2);
      rs += __shfl_xor(rs, 4);
      rs += __shfl_xor(rs, 8);
      if (lrow == 0) atomicAdd(&lsum[b * TT + q], rs);
    }
  }
}

// ---------------------------------------------------------------------------
// PV balanced pairing: block handles q-strips mt=p and 15-p. grid 512.
// ---------------------------------------------------------------------------
__global__ __launch_bounds__(256) void pv_gemm(const short* __restrict__ Pu,
                                               const short* __restrict__ Vt,
                                               const float* __restrict__ lsum,
                                               float* __restrict__ out) {
  int f = blockIdx.x;
  int b = f & 7;
  int j = f >> 3;          // [0,64)
  int p = j >> 3;          // [0,8)
  int nt = j & 7;
  int n0 = nt * 128;

  __shared__ __align__(16) short As[128 * 64];
  __shared__ __align__(16) short Bs[128 * 64];
  int tid = threadIdx.x;
  int lane = tid & 63, wid = tid >> 6, wr = wid >> 1, wc = wid & 1;
  const short* P = Pu + (size_t)b * TT * TT;
  const short* V = Vt + (size_t)b * AA * TT;
  int lrow = lane & 15, lk4 = (lane >> 4) * 4;

#pragma unroll
  for (int s = 0; s < 2; ++s) {
    int mt = s ? (15 - p) : p;
    int q0 = mt * 128;
    f32x4 acc[4][4];
#pragma unroll
    for (int i = 0; i < 4; ++i)
#pragma unroll
      for (int jj = 0; jj < 4; ++jj) acc[i][jj] = (f32x4){0.f, 0.f, 0.f, 0.f};

    int kend = q0 + 128;
    for (int k0 = 0; k0 < kend; k0 += 64) {
      stage_tile(P + (size_t)q0 * TT + k0, TT, As, tid);
      stage_tile(V + (size_t)n0 * TT + k0, TT, Bs, tid);
      __syncthreads();
      mfma_step(As, Bs, acc, lane, wr, wc);
      __syncthreads();
    }
#pragma unroll
    for (int i = 0; i < 4; ++i) {
#pragma unroll
      for (int r = 0; r < 4; ++r) {
        int q = q0 + wr * 64 + i * 16 + lk4 + r;
        float linv = 1.0f / lsum[b * TT + q];
#pragma unroll
        for (int jj = 0; jj < 4; ++jj) {
          int d = n0 + wc * 64 + jj * 16 + lrow;
          out[((size_t)(b * TT + q)) * AA + d] = acc[i][jj][r] * linv;
        }
      }
    }
  }
}

extern "C" void kernel_launch(void* const* d_in, const int* in_sizes, int n_in,
                              void* d_out, int out_size, void* d_ws,
                              size_t ws_size, hipStream_t stream) {
  const float* x = (const float*)d_in[0];
  const float* Wq = (const float*)d_in[1];
  const float* Wk = (const float*)d_in[2];
  const float* Wv = (const float*)d_in[3];

  char* ws = (char*)d_ws;
  size_t oWb = 0;
  size_t oQb = oWb + (size_t)3 * AA * EE * 2;   // 6 MB weights
  size_t oKb = oQb + (size_t)MM * AA * 2;
  size_t oVb = oKb + (size_t)MM * AA * 2;
  size_t oVt = oVb + (size_t)MM * AA * 2;
  size_t oLs = oVt + (size_t)MM * AA * 2;
  size_t oXb = oLs + (size_t)MM * 4;
  size_t oPu = oXb;  // Pu (67MB) overlaps Xb (33MB): Xb dead after qkv

  short* Wb = (short*)(ws + oWb);
  short* Qb = (short*)(ws + oQb);
  short* Kb = (short*)(ws + oKb);
  short* Vb = (short*)(ws + oVb);
  short* Vt = (short*)(ws + oVt);
  float* Ls = (float*)(ws + oLs);
  short* Xb = (short*)(ws + oXb);
  short* Pu = (short*)(ws + oPu);

  cvt_bf16<<<2048, 256, 0, stream>>>(x, Xb, MM * EE / 4);
  cvt_w3<<<768, 256, 0, stream>>>(Wq, Wk, Wv, Wb);
  hipMemsetAsync(Ls, 0, (size_t)MM * 4, stream);

  qkv_gemm8<<<768, 512, 0, stream>>>(Xb, Wb, Qb);
  transpose_v<<<dim3(32, 16, 8), 256, 0, stream>>>(Vb, Vt);
  score_gemm<<<1088, 256, 0, stream>>>(Qb, Kb, Pu, Ls);
  pv_gemm<<<512, 256, 0, stream>>>(Pu, Vt, Ls, (float*)d_out);
}